// Round 6
// baseline (1140.997 us; speedup 1.0000x reference)
//
#include <hip/hip_runtime.h>

// SJModel: 3x3 SAME conv (fp32, no bias) + 8-step LIF (tau=2, hard reset, v_th=1)
// x[T=8][B=16][Cin=64][H=64][W=64], W[Cout=64][Cin=64][3][3]
// out = spikes [T][B][Cout=64][H][W] fp32 (0/1)
//
// R6: LDS halo staging. Zero-padded 6x66 input tiles staged per 4-ci group
// (double-buffered, 12.7 KB LDS, still 8 blocks/CU). Inner loop per ci:
// 9 ds_read + 72 FMA, zero boundary cndmasks, no global-load latency chains.
// Per-output accumulation order (ci asc -> kh -> kw, fmaf) is IDENTICAL to
// R2/R5 => bitwise-identical spikes (absmax 0.0 preserved).

#define T_STEPS 8
#define B_SZ    16
#define CIN     64
#define COUT    64
#define H_SZ    64
#define W_SZ    64
#define CO_BLK  8
#define NCB     (COUT / CO_BLK)   // 8 co-chunks
#define G_CI    4                 // ci per staged group
#define NGRP    (CIN / G_CI)      // 16 groups

// W[co][ci][kh][kw] -> wt[ci][kh][cb][kw][j]  (24 contiguous per (ci,kh,cb))
__global__ void wt_transpose(const float* __restrict__ W, float* __restrict__ wt) {
    int idx = blockIdx.x * blockDim.x + threadIdx.x;
    if (idx >= COUT * CIN * 9) return;
    int kw = idx % 3;
    int kh = (idx / 3) % 3;
    int ci = (idx / 9) % CIN;
    int co = idx / (9 * CIN);
    int cb = co / CO_BLK, j = co % CO_BLK;
    wt[((((ci * 3 + kh) * NCB + cb) * 3) + kw) * CO_BLK + j] = W[idx];
}

__global__ void __launch_bounds__(256, 8)
lif_conv(const float* __restrict__ x, const float* __restrict__ wt,
         float* __restrict__ out) {
    // double-buffered halo tile: [buf][ci_local][row(-1..4)][col(-1..64)]
    __shared__ float lds[2][G_CI][6][66];

    const int w  = threadIdx.x;          // 0..63, lane = W dim
    const int ty = threadIdx.y;          // 0..3 (wave-uniform)
    const int h0 = blockIdx.x * 4;
    const int b  = blockIdx.y;           // 0..15
    const int cb = blockIdx.z;           // 0..7 co-chunk

    float v[CO_BLK];
#pragma unroll
    for (int j = 0; j < CO_BLK; ++j) v[j] = 0.f;

    // stage 4 ci planes' 6x66 zero-padded halo rows into lds[buf]
    auto stage = [&](const float* __restrict__ xt, int cg, int buf) {
#pragma unroll
        for (int ci_l = 0; ci_l < G_CI; ++ci_l) {
#pragma unroll
            for (int rr0 = 0; rr0 < 2; ++rr0) {
                const int rr = ty + rr0 * 4;          // rows 0..5 over ty
                if (rr < 6) {
                    const int ih = h0 + rr - 1;
                    const bool hv = (unsigned)ih < (unsigned)H_SZ;
                    const float* src = xt + (size_t)(cg + ci_l) * (H_SZ * W_SZ)
                                     + ih * W_SZ;
                    // col = w  <-> iw = w-1
                    float v0 = (hv && w > 0) ? src[w - 1] : 0.f;
                    lds[buf][ci_l][rr][w] = v0;
                    if (w < 2) {                      // cols 64,65 <-> iw 63,64
                        float v1 = (hv && w == 0) ? src[63] : 0.f;
                        lds[buf][ci_l][rr][64 + w] = v1;
                    }
                }
            }
        }
    };

    int cur = 0;
    {
        const float* xt0 = x + (size_t)(0 * B_SZ + b) * CIN * (H_SZ * W_SZ);
        stage(xt0, 0, 0);
    }

    for (int t = 0; t < T_STEPS; ++t) {
        const float* xt  = x + (size_t)(t * B_SZ + b) * CIN * (H_SZ * W_SZ);
        const float* xtn = x + (size_t)((t + 1) * B_SZ + b) * CIN * (H_SZ * W_SZ);

        float acc[CO_BLK];
#pragma unroll
        for (int j = 0; j < CO_BLK; ++j) acc[j] = 0.f;

        for (int g = 0; g < NGRP; ++g) {
            __syncthreads();
            // prefetch next group into the other buffer
            if (g < NGRP - 1)       stage(xt,  (g + 1) * G_CI, cur ^ 1);
            else if (t < T_STEPS-1) stage(xtn, 0,              cur ^ 1);

#pragma unroll
            for (int ci_l = 0; ci_l < G_CI; ++ci_l) {
                const int ci = g * G_CI + ci_l;
                // lane's tap base: row ty (=ih h-1 tap), col w (=iw w-1 tap)
                const float* xb = &lds[cur][ci_l][ty][w];
#pragma unroll
                for (int kh = 0; kh < 3; ++kh) {
                    const float* wr = wt
                        + (size_t)(((ci * 3 + kh) * NCB + cb) * 3) * CO_BLK;
#pragma unroll
                    for (int kw = 0; kw < 3; ++kw) {
                        const float xvv = xb[kh * 66 + kw];
#pragma unroll
                        for (int j = 0; j < CO_BLK; ++j)
                            acc[j] = fmaf(xvv, wr[kw * CO_BLK + j], acc[j]);
                    }
                }
            }
            cur ^= 1;
        }

        // LIF: charge (np op order), fire, hard reset; write spikes
        size_t obase = ((size_t)(t * B_SZ + b) * COUT + cb * CO_BLK) * (H_SZ * W_SZ)
                     + (size_t)(h0 + ty) * W_SZ + w;
#pragma unroll
        for (int j = 0; j < CO_BLK; ++j) {
            float vv = v[j];
            vv = vv + (acc[j] - vv) * 0.5f;          // charge: v + (z-v)/2
            float s = (vv >= 1.0f) ? 1.f : 0.f;      // fire
            vv = (vv >= 1.0f) ? 0.f : vv;            // hard reset
            v[j] = vv;
            out[obase + (size_t)j * (H_SZ * W_SZ)] = s;
        }
    }
}

extern "C" void kernel_launch(void* const* d_in, const int* in_sizes, int n_in,
                              void* d_out, int out_size, void* d_ws, size_t ws_size,
                              hipStream_t stream) {
    const float* x  = (const float*)d_in[0];
    const float* W  = (const float*)d_in[1];
    float* out = (float*)d_out;
    float* wt  = (float*)d_ws;   // 64*64*9*4 = 147456 B scratch

    wt_transpose<<<dim3((COUT * CIN * 9 + 255) / 256), dim3(256), 0, stream>>>(W, wt);
    lif_conv<<<dim3(16, 16, 8), dim3(64, 4, 1), 0, stream>>>(x, wt, out);
}

// Round 7
// 919.159 us; speedup vs baseline: 1.2413x; 1.2413x over previous
//
#include <hip/hip_runtime.h>

// SJModel: 3x3 SAME conv (fp32, no bias) + 8-step LIF (tau=2, hard reset, v_th=1)
// x[T=8][B=16][Cin=64][H=64][W=64], W[Cout=64][Cin=64][3][3]
// out = spikes [T][B][Cout=64][H][W] fp32 (0/1)
//
// R7: revert R6's LDS halo (barrier-phase too short -> stalls). Register-block
// both dims: thread owns 2 adjacent h-rows x 8 co; 12 x-loads/ci feed 144
// FMAs; weights loaded as explicit float4 (6 per (ci,kh)), layout
// [cb][ci][kh][kw][j]. launch_bounds(256,4) frees VGPRs for deep scheduling.
// Per-output fmaf order (ci->kh->kw) identical to R5 => bitwise-same spikes.

#define T_STEPS 8
#define B_SZ    16
#define CIN     64
#define COUT    64
#define H_SZ    64
#define W_SZ    64
#define CO_BLK  8
#define NCB     (COUT / CO_BLK)   // 8 co-chunks
#define PX      2                 // adjacent h-rows per thread

// W[co][ci][kh][kw] -> wt[cb][ci][kh][kw][j]
__global__ void wt_transpose(const float* __restrict__ W, float* __restrict__ wt) {
    int idx = blockIdx.x * blockDim.x + threadIdx.x;
    if (idx >= COUT * CIN * 9) return;
    int kw = idx % 3;
    int kh = (idx / 3) % 3;
    int ci = (idx / 9) % CIN;
    int co = idx / (9 * CIN);
    int cb = co / CO_BLK, j = co % CO_BLK;
    wt[(((size_t)(cb * CIN + ci) * 3 + kh) * 3 + kw) * CO_BLK + j] = W[idx];
}

__global__ void __launch_bounds__(256, 4)
lif_conv(const float* __restrict__ x, const float* __restrict__ wt,
         float* __restrict__ out) {
    const int w  = threadIdx.x;              // 0..63, lane = W dim (coalesced)
    const int ty = threadIdx.y;              // 0..3 (wave-uniform)
    const int h0 = blockIdx.x * 8 + ty * 2;  // thread owns rows h0, h0+1
    const int b  = blockIdx.y;               // 0..15
    const int cb = blockIdx.z;               // 0..7 co-chunk

    float v[PX][CO_BLK];
#pragma unroll
    for (int p = 0; p < PX; ++p)
#pragma unroll
        for (int j = 0; j < CO_BLK; ++j) v[p][j] = 0.f;

    const bool wm0 = (w > 0), wm2 = (w < W_SZ - 1);
    const bool hvT = (h0 > 0);             // input row h0-1 valid (wave-uniform)
    const bool hvB = (h0 + 2 < H_SZ);      // input row h0+2 valid (wave-uniform)

    const float* wcb = wt + (size_t)cb * CIN * 9 * CO_BLK;

    for (int t = 0; t < T_STEPS; ++t) {
        const float* xt = x + (size_t)(t * B_SZ + b) * CIN * (H_SZ * W_SZ)
                        + h0 * W_SZ + w;

        float acc[PX][CO_BLK];
#pragma unroll
        for (int p = 0; p < PX; ++p)
#pragma unroll
            for (int j = 0; j < CO_BLK; ++j) acc[p][j] = 0.f;

        for (int ci = 0; ci < CIN; ++ci) {
            const float* xb = xt + ci * (H_SZ * W_SZ);

            // 4 input rows (h0-1 .. h0+2) x 3 cols, zero-padded halo
            float xr[PX + 2][3];
            xr[0][0] = (hvT && wm0) ? xb[-W_SZ - 1] : 0.f;
            xr[0][1] =  hvT         ? xb[-W_SZ]     : 0.f;
            xr[0][2] = (hvT && wm2) ? xb[-W_SZ + 1] : 0.f;
            xr[1][0] =  wm0 ? xb[-1]        : 0.f;
            xr[1][1] =        xb[0];
            xr[1][2] =  wm2 ? xb[1]         : 0.f;
            xr[2][0] =  wm0 ? xb[W_SZ - 1]  : 0.f;
            xr[2][1] =        xb[W_SZ];
            xr[2][2] =  wm2 ? xb[W_SZ + 1]  : 0.f;
            xr[3][0] = (hvB && wm0) ? xb[2 * W_SZ - 1] : 0.f;
            xr[3][1] =  hvB         ? xb[2 * W_SZ]     : 0.f;
            xr[3][2] = (hvB && wm2) ? xb[2 * W_SZ + 1] : 0.f;

            const float* wci = wcb + (size_t)ci * 9 * CO_BLK;
#pragma unroll
            for (int kh = 0; kh < 3; ++kh) {
                const float4* q = (const float4*)(wci + kh * 3 * CO_BLK);
                const float4 q00 = q[0], q01 = q[1];   // kw=0, j 0-3 / 4-7
                const float4 q10 = q[2], q11 = q[3];   // kw=1
                const float4 q20 = q[4], q21 = q[5];   // kw=2
#pragma unroll
                for (int p = 0; p < PX; ++p) {
                    const float x0 = xr[p + kh][0];
                    const float x1 = xr[p + kh][1];
                    const float x2 = xr[p + kh][2];
                    // kw=0
                    acc[p][0] = fmaf(x0, q00.x, acc[p][0]);
                    acc[p][1] = fmaf(x0, q00.y, acc[p][1]);
                    acc[p][2] = fmaf(x0, q00.z, acc[p][2]);
                    acc[p][3] = fmaf(x0, q00.w, acc[p][3]);
                    acc[p][4] = fmaf(x0, q01.x, acc[p][4]);
                    acc[p][5] = fmaf(x0, q01.y, acc[p][5]);
                    acc[p][6] = fmaf(x0, q01.z, acc[p][6]);
                    acc[p][7] = fmaf(x0, q01.w, acc[p][7]);
                    // kw=1
                    acc[p][0] = fmaf(x1, q10.x, acc[p][0]);
                    acc[p][1] = fmaf(x1, q10.y, acc[p][1]);
                    acc[p][2] = fmaf(x1, q10.z, acc[p][2]);
                    acc[p][3] = fmaf(x1, q10.w, acc[p][3]);
                    acc[p][4] = fmaf(x1, q11.x, acc[p][4]);
                    acc[p][5] = fmaf(x1, q11.y, acc[p][5]);
                    acc[p][6] = fmaf(x1, q11.z, acc[p][6]);
                    acc[p][7] = fmaf(x1, q11.w, acc[p][7]);
                    // kw=2
                    acc[p][0] = fmaf(x2, q20.x, acc[p][0]);
                    acc[p][1] = fmaf(x2, q20.y, acc[p][1]);
                    acc[p][2] = fmaf(x2, q20.z, acc[p][2]);
                    acc[p][3] = fmaf(x2, q20.w, acc[p][3]);
                    acc[p][4] = fmaf(x2, q21.x, acc[p][4]);
                    acc[p][5] = fmaf(x2, q21.y, acc[p][5]);
                    acc[p][6] = fmaf(x2, q21.z, acc[p][6]);
                    acc[p][7] = fmaf(x2, q21.w, acc[p][7]);
                }
            }
        }

        // LIF: charge (np op order), fire, hard reset; write spikes
#pragma unroll
        for (int p = 0; p < PX; ++p) {
            size_t obase = ((size_t)(t * B_SZ + b) * COUT + cb * CO_BLK)
                         * (H_SZ * W_SZ) + (size_t)(h0 + p) * W_SZ + w;
#pragma unroll
            for (int j = 0; j < CO_BLK; ++j) {
                float vv = v[p][j];
                vv = vv + (acc[p][j] - vv) * 0.5f;       // charge: v + (z-v)/2
                float s = (vv >= 1.0f) ? 1.f : 0.f;      // fire
                vv = (vv >= 1.0f) ? 0.f : vv;            // hard reset
                v[p][j] = vv;
                out[obase + (size_t)j * (H_SZ * W_SZ)] = s;
            }
        }
    }
}

extern "C" void kernel_launch(void* const* d_in, const int* in_sizes, int n_in,
                              void* d_out, int out_size, void* d_ws, size_t ws_size,
                              hipStream_t stream) {
    const float* x  = (const float*)d_in[0];
    const float* W  = (const float*)d_in[1];
    float* out = (float*)d_out;
    float* wt  = (float*)d_ws;   // 64*64*9*4 = 147456 B scratch

    wt_transpose<<<dim3((COUT * CIN * 9 + 255) / 256), dim3(256), 0, stream>>>(W, wt);
    lif_conv<<<dim3(8, 16, 8), dim3(64, 4, 1), 0, stream>>>(x, wt, out);
}

// Round 8
// 654.727 us; speedup vs baseline: 1.7427x; 1.4039x over previous
//
#include <hip/hip_runtime.h>

// SJModel: 3x3 SAME conv (fp32, no bias) + 8-step LIF (tau=2, hard reset, v_th=1)
// x[T=8][B=16][Cin=64][H=64][W=64], W[Cout=64][Cin=64][3][3]
// out = spikes [T][B][Cout=64][H][W] fp32 (0/1)
//
// R8: R7 + TB=2 time-blocking: acc for t,t+1 computed jointly so each weight
// float4 feeds 2x the FMAs and two independent x-load streams stay in flight.
// launch_bounds(256,3) raises the VGPR cap (~170) so hoisted loads live in
// registers (R7 compiled to just 36 VGPRs -> no latency hiding).
// Per-output fmaf order (ci->kh->kw) identical to R5/R7 => bitwise-same spikes.

#define T_STEPS 8
#define B_SZ    16
#define CIN     64
#define COUT    64
#define H_SZ    64
#define W_SZ    64
#define HW      (H_SZ * W_SZ)
#define CO_BLK  8
#define NCB     (COUT / CO_BLK)   // 8 co-chunks
#define PX      2                 // adjacent h-rows per thread
#define TB      2                 // time steps blocked per conv pass

// W[co][ci][kh][kw] -> wt[cb][ci][kh][kw][j]
__global__ void wt_transpose(const float* __restrict__ W, float* __restrict__ wt) {
    int idx = blockIdx.x * blockDim.x + threadIdx.x;
    if (idx >= COUT * CIN * 9) return;
    int kw = idx % 3;
    int kh = (idx / 3) % 3;
    int ci = (idx / 9) % CIN;
    int co = idx / (9 * CIN);
    int cb = co / CO_BLK, j = co % CO_BLK;
    wt[(((size_t)(cb * CIN + ci) * 3 + kh) * 3 + kw) * CO_BLK + j] = W[idx];
}

__global__ void __launch_bounds__(256, 3)
lif_conv(const float* __restrict__ x, const float* __restrict__ wt,
         float* __restrict__ out) {
    const int w  = threadIdx.x;              // 0..63, lane = W dim (coalesced)
    const int ty = threadIdx.y;              // 0..3 (wave-uniform)
    const int h0 = blockIdx.x * 8 + ty * 2;  // thread owns rows h0, h0+1
    const int b  = blockIdx.y;               // 0..15
    const int cb = blockIdx.z;               // 0..7 co-chunk

    float v[PX][CO_BLK];
#pragma unroll
    for (int p = 0; p < PX; ++p)
#pragma unroll
        for (int j = 0; j < CO_BLK; ++j) v[p][j] = 0.f;

    const bool wm0 = (w > 0), wm2 = (w < W_SZ - 1);
    const bool hvT = (h0 > 0);             // input row h0-1 valid (wave-uniform)
    const bool hvB = (h0 + 2 < H_SZ);      // input row h0+2 valid (wave-uniform)

    const float* wcb = wt + (size_t)cb * CIN * 9 * CO_BLK;

    for (int t = 0; t < T_STEPS; t += TB) {
        const float* xt0 = x + (size_t)(t * B_SZ + b) * CIN * HW + h0 * W_SZ + w;
        const float* xt1 = xt0 + (size_t)B_SZ * CIN * HW;   // t+1 plane

        float acc[TB][PX][CO_BLK];
#pragma unroll
        for (int tt = 0; tt < TB; ++tt)
#pragma unroll
            for (int p = 0; p < PX; ++p)
#pragma unroll
                for (int j = 0; j < CO_BLK; ++j) acc[tt][p][j] = 0.f;

        for (int ci = 0; ci < CIN; ++ci) {
            // 2 time-planes x 4 rows (h0-1..h0+2) x 3 cols, zero-padded halo
            float xr[TB][PX + 2][3];
#pragma unroll
            for (int tt = 0; tt < TB; ++tt) {
                const float* xb = (tt == 0 ? xt0 : xt1) + ci * HW;
                xr[tt][0][0] = (hvT && wm0) ? xb[-W_SZ - 1] : 0.f;
                xr[tt][0][1] =  hvT         ? xb[-W_SZ]     : 0.f;
                xr[tt][0][2] = (hvT && wm2) ? xb[-W_SZ + 1] : 0.f;
                xr[tt][1][0] =  wm0 ? xb[-1]        : 0.f;
                xr[tt][1][1] =        xb[0];
                xr[tt][1][2] =  wm2 ? xb[1]         : 0.f;
                xr[tt][2][0] =  wm0 ? xb[W_SZ - 1]  : 0.f;
                xr[tt][2][1] =        xb[W_SZ];
                xr[tt][2][2] =  wm2 ? xb[W_SZ + 1]  : 0.f;
                xr[tt][3][0] = (hvB && wm0) ? xb[2 * W_SZ - 1] : 0.f;
                xr[tt][3][1] =  hvB         ? xb[2 * W_SZ]     : 0.f;
                xr[tt][3][2] = (hvB && wm2) ? xb[2 * W_SZ + 1] : 0.f;
            }

            const float* wci = wcb + (size_t)ci * 9 * CO_BLK;
#pragma unroll
            for (int kh = 0; kh < 3; ++kh) {
                const float4* q = (const float4*)(wci + kh * 3 * CO_BLK);
                const float4 q00 = q[0], q01 = q[1];   // kw=0, j 0-3 / 4-7
                const float4 q10 = q[2], q11 = q[3];   // kw=1
                const float4 q20 = q[4], q21 = q[5];   // kw=2
#pragma unroll
                for (int tt = 0; tt < TB; ++tt) {
#pragma unroll
                    for (int p = 0; p < PX; ++p) {
                        const float x0 = xr[tt][p + kh][0];
                        const float x1 = xr[tt][p + kh][1];
                        const float x2 = xr[tt][p + kh][2];
                        float* a = acc[tt][p];
                        a[0] = fmaf(x0, q00.x, a[0]);
                        a[1] = fmaf(x0, q00.y, a[1]);
                        a[2] = fmaf(x0, q00.z, a[2]);
                        a[3] = fmaf(x0, q00.w, a[3]);
                        a[4] = fmaf(x0, q01.x, a[4]);
                        a[5] = fmaf(x0, q01.y, a[5]);
                        a[6] = fmaf(x0, q01.z, a[6]);
                        a[7] = fmaf(x0, q01.w, a[7]);
                        a[0] = fmaf(x1, q10.x, a[0]);
                        a[1] = fmaf(x1, q10.y, a[1]);
                        a[2] = fmaf(x1, q10.z, a[2]);
                        a[3] = fmaf(x1, q10.w, a[3]);
                        a[4] = fmaf(x1, q11.x, a[4]);
                        a[5] = fmaf(x1, q11.y, a[5]);
                        a[6] = fmaf(x1, q11.z, a[6]);
                        a[7] = fmaf(x1, q11.w, a[7]);
                        a[0] = fmaf(x2, q20.x, a[0]);
                        a[1] = fmaf(x2, q20.y, a[1]);
                        a[2] = fmaf(x2, q20.z, a[2]);
                        a[3] = fmaf(x2, q20.w, a[3]);
                        a[4] = fmaf(x2, q21.x, a[4]);
                        a[5] = fmaf(x2, q21.y, a[5]);
                        a[6] = fmaf(x2, q21.z, a[6]);
                        a[7] = fmaf(x2, q21.w, a[7]);
                    }
                }
            }
        }

        // LIF for t then t+1 (sequential in tt), np op order; nontemporal stores
#pragma unroll
        for (int tt = 0; tt < TB; ++tt) {
#pragma unroll
            for (int p = 0; p < PX; ++p) {
                size_t obase = ((size_t)((t + tt) * B_SZ + b) * COUT + cb * CO_BLK) * HW
                             + (size_t)(h0 + p) * W_SZ + w;
#pragma unroll
                for (int j = 0; j < CO_BLK; ++j) {
                    float vv = v[p][j];
                    vv = vv + (acc[tt][p][j] - vv) * 0.5f;   // charge: v + (z-v)/2
                    float s = (vv >= 1.0f) ? 1.f : 0.f;      // fire
                    vv = (vv >= 1.0f) ? 0.f : vv;            // hard reset
                    v[p][j] = vv;
                    __builtin_nontemporal_store(s, &out[obase + (size_t)j * HW]);
                }
            }
        }
    }
}

extern "C" void kernel_launch(void* const* d_in, const int* in_sizes, int n_in,
                              void* d_out, int out_size, void* d_ws, size_t ws_size,
                              hipStream_t stream) {
    const float* x  = (const float*)d_in[0];
    const float* W  = (const float*)d_in[1];
    float* out = (float*)d_out;
    float* wt  = (float*)d_ws;   // 64*64*9*4 = 147456 B scratch

    wt_transpose<<<dim3((COUT * CIN * 9 + 255) / 256), dim3(256), 0, stream>>>(W, wt);
    lif_conv<<<dim3(8, 16, 8), dim3(64, 4, 1), 0, stream>>>(x, wt, out);
}

// Round 11
// 617.589 us; speedup vs baseline: 1.8475x; 1.0601x over previous
//
#include <hip/hip_runtime.h>

// SJModel: 3x3 SAME conv (fp32, no bias) + 8-step LIF (tau=2, hard reset, v_th=1)
// x[T=8][B=16][Cin=64][H=64][W=64], W[Cout=64][Cin=64][3][3]
// out = spikes [T][B][Cout=64][H][W] fp32 (0/1)
//
// R9 (3rd submit; two broker timeouts, kernel never ran): R8 + shuffle-halo.
// The +-1 column taps are neighbor lanes' center values (lane == w spans the
// full row; w=0/63 boundary zeros == shuffle edge zeros). Replace 16
// predicated column loads per ci with 4+4 center loads + __shfl_up/down on
// the idle LDS pipe. Bitwise-identical arithmetic (same bits, same fmaf
// order) => absmax 0.0.

#define T_STEPS 8
#define B_SZ    16
#define CIN     64
#define COUT    64
#define H_SZ    64
#define W_SZ    64
#define HW      (H_SZ * W_SZ)
#define CO_BLK  8
#define NCB     (COUT / CO_BLK)   // 8 co-chunks
#define PX      2                 // adjacent h-rows per thread
#define TB      2                 // time steps blocked per conv pass

// W[co][ci][kh][kw] -> wt[cb][ci][kh][kw][j]
__global__ void wt_transpose(const float* __restrict__ W, float* __restrict__ wt) {
    int idx = blockIdx.x * blockDim.x + threadIdx.x;
    if (idx >= COUT * CIN * 9) return;
    int kw = idx % 3;
    int kh = (idx / 3) % 3;
    int ci = (idx / 9) % CIN;
    int co = idx / (9 * CIN);
    int cb = co / CO_BLK, j = co % CO_BLK;
    wt[(((size_t)(cb * CIN + ci) * 3 + kh) * 3 + kw) * CO_BLK + j] = W[idx];
}

__global__ void __launch_bounds__(256, 3)
lif_conv(const float* __restrict__ x, const float* __restrict__ wt,
         float* __restrict__ out) {
    const int w  = threadIdx.x;              // 0..63, lane = W dim (coalesced)
    const int ty = threadIdx.y;              // 0..3 (wave-uniform)
    const int h0 = blockIdx.x * 8 + ty * 2;  // thread owns rows h0, h0+1
    const int b  = blockIdx.y;               // 0..15
    const int cb = blockIdx.z;               // 0..7 co-chunk

    float v[PX][CO_BLK];
#pragma unroll
    for (int p = 0; p < PX; ++p)
#pragma unroll
        for (int j = 0; j < CO_BLK; ++j) v[p][j] = 0.f;

    const bool wm0 = (w > 0), wm2 = (w < W_SZ - 1);
    const bool hvT = (h0 > 0);             // input row h0-1 valid (wave-uniform)
    const bool hvB = (h0 + 2 < H_SZ);      // input row h0+2 valid (wave-uniform)

    const float* wcb = wt + (size_t)cb * CIN * 9 * CO_BLK;

    for (int t = 0; t < T_STEPS; t += TB) {
        const float* xt0 = x + (size_t)(t * B_SZ + b) * CIN * HW + h0 * W_SZ + w;
        const float* xt1 = xt0 + (size_t)B_SZ * CIN * HW;   // t+1 plane

        float acc[TB][PX][CO_BLK];
#pragma unroll
        for (int tt = 0; tt < TB; ++tt)
#pragma unroll
            for (int p = 0; p < PX; ++p)
#pragma unroll
                for (int j = 0; j < CO_BLK; ++j) acc[tt][p][j] = 0.f;

        for (int ci = 0; ci < CIN; ++ci) {
            // 2 time-planes x 4 center rows (h0-1..h0+2); halo cols via shuffle
            float xr[TB][PX + 2][3];
#pragma unroll
            for (int tt = 0; tt < TB; ++tt) {
                const float* xb = (tt == 0 ? xt0 : xt1) + ci * HW;
                float c[4];
                c[0] = hvT ? xb[-W_SZ]     : 0.f;
                c[1] =       xb[0];
                c[2] =       xb[W_SZ];
                c[3] = hvB ? xb[2 * W_SZ]  : 0.f;
#pragma unroll
                for (int r = 0; r < 4; ++r) {
                    float lu = __shfl_up(c[r], 1);    // lane w <- w-1
                    float rd = __shfl_down(c[r], 1);  // lane w <- w+1
                    xr[tt][r][0] = wm0 ? lu : 0.f;    // x[w-1] (0 at w=0)
                    xr[tt][r][1] = c[r];
                    xr[tt][r][2] = wm2 ? rd : 0.f;    // x[w+1] (0 at w=63)
                }
            }

            const float* wci = wcb + (size_t)ci * 9 * CO_BLK;
#pragma unroll
            for (int kh = 0; kh < 3; ++kh) {
                const float4* q = (const float4*)(wci + kh * 3 * CO_BLK);
                const float4 q00 = q[0], q01 = q[1];   // kw=0, j 0-3 / 4-7
                const float4 q10 = q[2], q11 = q[3];   // kw=1
                const float4 q20 = q[4], q21 = q[5];   // kw=2
#pragma unroll
                for (int tt = 0; tt < TB; ++tt) {
#pragma unroll
                    for (int p = 0; p < PX; ++p) {
                        const float x0 = xr[tt][p + kh][0];
                        const float x1 = xr[tt][p + kh][1];
                        const float x2 = xr[tt][p + kh][2];
                        float* a = acc[tt][p];
                        a[0] = fmaf(x0, q00.x, a[0]);
                        a[1] = fmaf(x0, q00.y, a[1]);
                        a[2] = fmaf(x0, q00.z, a[2]);
                        a[3] = fmaf(x0, q00.w, a[3]);
                        a[4] = fmaf(x0, q01.x, a[4]);
                        a[5] = fmaf(x0, q01.y, a[5]);
                        a[6] = fmaf(x0, q01.z, a[6]);
                        a[7] = fmaf(x0, q01.w, a[7]);
                        a[0] = fmaf(x1, q10.x, a[0]);
                        a[1] = fmaf(x1, q10.y, a[1]);
                        a[2] = fmaf(x1, q10.z, a[2]);
                        a[3] = fmaf(x1, q10.w, a[3]);
                        a[4] = fmaf(x1, q11.x, a[4]);
                        a[5] = fmaf(x1, q11.y, a[5]);
                        a[6] = fmaf(x1, q11.z, a[6]);
                        a[7] = fmaf(x1, q11.w, a[7]);
                        a[0] = fmaf(x2, q20.x, a[0]);
                        a[1] = fmaf(x2, q20.y, a[1]);
                        a[2] = fmaf(x2, q20.z, a[2]);
                        a[3] = fmaf(x2, q20.w, a[3]);
                        a[4] = fmaf(x2, q21.x, a[4]);
                        a[5] = fmaf(x2, q21.y, a[5]);
                        a[6] = fmaf(x2, q21.z, a[6]);
                        a[7] = fmaf(x2, q21.w, a[7]);
                    }
                }
            }
        }

        // LIF for t then t+1 (sequential in tt), np op order; nontemporal stores
#pragma unroll
        for (int tt = 0; tt < TB; ++tt) {
#pragma unroll
            for (int p = 0; p < PX; ++p) {
                size_t obase = ((size_t)((t + tt) * B_SZ + b) * COUT + cb * CO_BLK) * HW
                             + (size_t)(h0 + p) * W_SZ + w;
#pragma unroll
                for (int j = 0; j < CO_BLK; ++j) {
                    float vv = v[p][j];
                    vv = vv + (acc[tt][p][j] - vv) * 0.5f;   // charge: v + (z-v)/2
                    float s = (vv >= 1.0f) ? 1.f : 0.f;      // fire
                    vv = (vv >= 1.0f) ? 0.f : vv;            // hard reset
                    v[p][j] = vv;
                    __builtin_nontemporal_store(s, &out[obase + (size_t)j * HW]);
                }
            }
        }
    }
}

extern "C" void kernel_launch(void* const* d_in, const int* in_sizes, int n_in,
                              void* d_out, int out_size, void* d_ws, size_t ws_size,
                              hipStream_t stream) {
    const float* x  = (const float*)d_in[0];
    const float* W  = (const float*)d_in[1];
    float* out = (float*)d_out;
    float* wt  = (float*)d_ws;   // 64*64*9*4 = 147456 B scratch

    wt_transpose<<<dim3((COUT * CIN * 9 + 255) / 256), dim3(256), 0, stream>>>(W, wt);
    lif_conv<<<dim3(8, 16, 8), dim3(64, 4, 1), 0, stream>>>(x, wt, out);
}